// Round 1
// baseline (375.108 us; speedup 1.0000x reference)
//
#include <hip/hip_runtime.h>

// Self-attention forward, MI355X (gfx950).
// B=2 S=2048 D=1024 H=16 HD=64. fp32 in/out, bf16 MFMA internally.
//
// Pipeline:
//   1. cast x -> bf16 (xb)
//   2. transpose-cast qkv_w (1024x3072) -> bf16 [n][k] (qkv_wt); same for out_w
//   3. gemm_bt<1>: qkv = xb @ qkv_w + b, epilogue scatters q(,*1/8)/k/v bf16 [b,h,s,hd]
//   4. flash_attn: online-softmax, 16x16x32 bf16 MFMA, writes attn bf16 (aliases xb)
//   5. gemm_bt<0>: out = attn @ out_w + out_b, fp32 -> d_out

typedef __bf16 bf16x8 __attribute__((ext_vector_type(8)));
typedef float f32x4 __attribute__((ext_vector_type(4)));
typedef unsigned short u16;
typedef u16 u16x8 __attribute__((ext_vector_type(8)));

#define NEG_INF (-__builtin_inff())

__device__ __forceinline__ u16 f2b(float f) {
    unsigned u = __builtin_bit_cast(unsigned, f);
    u += 0x7fffu + ((u >> 16) & 1u);   // round-to-nearest-even
    return (u16)(u >> 16);
}

__device__ __forceinline__ void gload_lds16(const u16* g, u16* l) {
    __builtin_amdgcn_global_load_lds(
        (__attribute__((address_space(1))) unsigned int*)(g),
        (__attribute__((address_space(3))) unsigned int*)(l),
        16u, 0, 0u);
}

// ---------------------------------------------------------------- cast x -> bf16
__global__ void cast_f32_bf16(const float* __restrict__ X, u16* __restrict__ Y, int n4)
{
    int i = blockIdx.x * blockDim.x + threadIdx.x;
    if (i >= n4) return;
    float4 v = ((const float4*)X)[i];
    ((ushort4*)Y)[i] = make_ushort4(f2b(v.x), f2b(v.y), f2b(v.z), f2b(v.w));
}

// ---------------------------------------- transpose-cast W[K][N] f32 -> Wt[N][K] bf16
__global__ void transpose_cast(const float* __restrict__ W, u16* __restrict__ Wt, int K, int N)
{
    __shared__ float tile[32][33];
    const int c0 = blockIdx.x * 32, r0 = blockIdx.y * 32;
    const int tc = threadIdx.x & 31, tr = threadIdx.x >> 5;   // tr in 0..7
#pragma unroll
    for (int i = 0; i < 4; ++i)
        tile[tr + i*8][tc] = W[(size_t)(r0 + tr + i*8) * N + c0 + tc];
    __syncthreads();
#pragma unroll
    for (int i = 0; i < 4; ++i) {
        int nn = tr + i*8;
        Wt[(size_t)(c0 + nn) * K + r0 + tc] = f2b(tile[tc][nn]);
    }
}

// ---------------------------------------------------------------- GEMM C = A * Bt^T
// A: [M][K] bf16 row-major. Bt: [N][K] bf16 row-major. 128x128 tile, BK=32,
// 256 threads = 2x2 waves, each wave 64x64 = 4x4 MFMA 16x16x32 frags (m97 pattern).
// MODE 0: Cf[m*N+n] = acc + bias[n]   (fp32 out)
// MODE 1: qkv scatter: n = t*1024 + h*64 + hd, m = b*2048 + s; q scaled by 1/8, bf16.
template<int MODE>
__global__ __launch_bounds__(256) void gemm_bt(
    const u16* __restrict__ A, const u16* __restrict__ Bt,
    const float* __restrict__ bias, float* __restrict__ Cf,
    u16* __restrict__ qb, u16* __restrict__ kb, u16* __restrict__ vb,
    int M, int N, int K)
{
    __shared__ __align__(16) u16 As[128 * 32];
    __shared__ __align__(16) u16 Bs[128 * 32];
    const int tid  = threadIdx.x;
    const int wave = tid >> 6, lane = tid & 63;
    const int quad = lane >> 4, l16 = lane & 15;
    const int m0 = blockIdx.y * 128, n0 = blockIdx.x * 128;
    const int wm = (wave >> 1) * 64, wn = (wave & 1) * 64;

    f32x4 acc[4][4] = {};

    for (int kt = 0; kt < K; kt += 32) {
#pragma unroll
        for (int iss = 0; iss < 2; ++iss) {
            const int e = iss * 2048 + tid * 8;       // linear bf16 element in 128x32 tile
            const int row = e >> 5, col = e & 31;
            gload_lds16(A  + (size_t)(m0 + row) * K + kt + col, As + iss * 2048 + wave * 512);
            gload_lds16(Bt + (size_t)(n0 + row) * K + kt + col, Bs + iss * 2048 + wave * 512);
        }
        __syncthreads();
        bf16x8 af[4], bfr[4];
#pragma unroll
        for (int i = 0; i < 4; ++i) {
            af[i]  = *(const bf16x8*)(As + (wm + i*16 + l16) * 32 + quad * 8);
            bfr[i] = *(const bf16x8*)(Bs + (wn + i*16 + l16) * 32 + quad * 8);
        }
#pragma unroll
        for (int i = 0; i < 4; ++i)
#pragma unroll
            for (int j = 0; j < 4; ++j)
                acc[i][j] = __builtin_amdgcn_mfma_f32_16x16x32_bf16(af[i], bfr[j], acc[i][j], 0, 0, 0);
        __syncthreads();
    }

#pragma unroll
    for (int i = 0; i < 4; ++i)
#pragma unroll
        for (int j = 0; j < 4; ++j)
#pragma unroll
            for (int r = 0; r < 4; ++r) {
                const int m = m0 + wm + i*16 + quad*4 + r;   // C/D: row = quad*4+reg
                const int n = n0 + wn + j*16 + l16;          //      col = lane&15
                float v = acc[i][j][r] + bias[n];
                if (MODE == 0) {
                    Cf[(size_t)m * N + n] = v;
                } else {
                    const int t = n >> 10, h = (n >> 6) & 15, hd = n & 63;
                    const int b = m >> 11, s = m & 2047;
                    const size_t idx = ((size_t)(b * 16 + h) * 2048 + s) * 64 + hd;
                    if (t == 0)      qb[idx] = f2b(v * 0.125f);   // fold softmax scale into q
                    else if (t == 1) kb[idx] = f2b(v);
                    else             vb[idx] = f2b(v);
                }
            }
}

// ---------------------------------------------------------------- flash attention
// grid (S/64=32, B*H=32), 256 threads = 4 waves x 16 q-rows. 32-key tiles, causal.
__global__ __launch_bounds__(256) void flash_attn(
    const u16* __restrict__ qb, const u16* __restrict__ kb, const u16* __restrict__ vb,
    u16* __restrict__ attn)
{
    __shared__ __align__(16) u16 ks[32 * 64];      // K tile [key][hd]
    __shared__ __align__(16) u16 vt[64 * 32];      // V tile transposed [hd][key]
    __shared__ __align__(16) u16 pl[4][16 * 32];   // per-wave P tile [q][key]
    const int tid  = threadIdx.x;
    const int wave = tid >> 6, lane = tid & 63;
    const int quad = lane >> 4, l16 = lane & 15;
    const int qt = blockIdx.x, bh = blockIdx.y;
    const size_t base = (size_t)bh * (2048 * 64);
    const int qrow0 = qt * 64 + wave * 16;

    // Q fragment: A layout, m=lane&15, k=quad*8+j; two k-halves of HD=64
    const bf16x8 qf0 = *(const bf16x8*)(qb + base + (size_t)(qrow0 + l16) * 64 + quad * 8);
    const bf16x8 qf1 = *(const bf16x8*)(qb + base + (size_t)(qrow0 + l16) * 64 + 32 + quad * 8);

    f32x4 of[4] = {};
    float mi[4] = {NEG_INF, NEG_INF, NEG_INF, NEG_INF};
    float li[4] = {0.f, 0.f, 0.f, 0.f};

    const int nkt = qt * 2 + 2;
    const int vrow = tid >> 3, vcol = (tid & 7) * 8;

    for (int kt = 0; kt < nkt; ++kt) {
        const int key0 = kt * 32;
        // stage K (flat 4KB copy, vectorized)
        u16x8 kv = *(const u16x8*)(kb + base + (size_t)key0 * 64 + tid * 8);
        *(u16x8*)(ks + tid * 8) = kv;
        // stage V transposed
        u16x8 vv = *(const u16x8*)(vb + base + (size_t)(key0 + vrow) * 64 + vcol);
#pragma unroll
        for (int j = 0; j < 8; ++j)
            vt[(vcol + j) * 32 + vrow] = vv[j];
        __syncthreads();

        // S = Q*K^T : two 16-key sub-tiles
        f32x4 sf[2] = {};
#pragma unroll
        for (int ns = 0; ns < 2; ++ns) {
            bf16x8 kf0 = *(const bf16x8*)(ks + (ns*16 + l16) * 64 + quad * 8);
            bf16x8 kf1 = *(const bf16x8*)(ks + (ns*16 + l16) * 64 + 32 + quad * 8);
            sf[ns] = __builtin_amdgcn_mfma_f32_16x16x32_bf16(qf0, kf0, sf[ns], 0, 0, 0);
            sf[ns] = __builtin_amdgcn_mfma_f32_16x16x32_bf16(qf1, kf1, sf[ns], 0, 0, 0);
        }

        // online softmax per q-row (rows = quad*4+r, key cols spread over 16 lanes)
#pragma unroll
        for (int r = 0; r < 4; ++r) {
            const int q_idx = qrow0 + quad * 4 + r;
            float s0 = sf[0][r]; if (key0 + l16      > q_idx) s0 = NEG_INF;
            float s1 = sf[1][r]; if (key0 + 16 + l16 > q_idx) s1 = NEG_INF;
            float mx = fmaxf(s0, s1);
            mx = fmaxf(mx, __shfl_xor(mx, 1));
            mx = fmaxf(mx, __shfl_xor(mx, 2));
            mx = fmaxf(mx, __shfl_xor(mx, 4));
            mx = fmaxf(mx, __shfl_xor(mx, 8));
            const float mnew  = fmaxf(mi[r], mx);
            const float p0    = __expf(s0 - mnew);
            const float p1    = __expf(s1 - mnew);
            const float alpha = __expf(mi[r] - mnew);
            mi[r] = mnew;
            float rs = p0 + p1;
            rs += __shfl_xor(rs, 1);
            rs += __shfl_xor(rs, 2);
            rs += __shfl_xor(rs, 4);
            rs += __shfl_xor(rs, 8);
            li[r] = li[r] * alpha + rs;
            of[0][r] *= alpha; of[1][r] *= alpha; of[2][r] *= alpha; of[3][r] *= alpha;
            pl[wave][(quad*4 + r) * 32 + l16]      = f2b(p0);
            pl[wave][(quad*4 + r) * 32 + 16 + l16] = f2b(p1);
        }

        // P*V: P as A-operand (LDS round-trip), V^T rows give contiguous B frags
        const bf16x8 pf = *(const bf16x8*)(&pl[wave][l16 * 32 + quad * 8]);
#pragma unroll
        for (int c = 0; c < 4; ++c) {
            bf16x8 vf = *(const bf16x8*)(vt + (c*16 + l16) * 32 + quad * 8);
            of[c] = __builtin_amdgcn_mfma_f32_16x16x32_bf16(pf, vf, of[c], 0, 0, 0);
        }
        __syncthreads();
    }

    const int b = bh >> 4, h = bh & 15;
#pragma unroll
    for (int r = 0; r < 4; ++r) {
        const float inv = 1.0f / li[r];
        const int s = qrow0 + quad * 4 + r;
        u16* dst = attn + ((size_t)(b * 2048 + s)) * 1024 + h * 64;
#pragma unroll
        for (int c = 0; c < 4; ++c)
            dst[c * 16 + l16] = f2b(of[c][r] * inv);
    }
}

// ---------------------------------------------------------------- launch
extern "C" void kernel_launch(void* const* d_in, const int* in_sizes, int n_in,
                              void* d_out, int out_size, void* d_ws, size_t ws_size,
                              hipStream_t stream)
{
    const float* x     = (const float*)d_in[0];
    const float* qkv_w = (const float*)d_in[1];
    const float* qkv_b = (const float*)d_in[2];
    const float* out_w = (const float*)d_in[3];
    const float* out_b = (const float*)d_in[4];
    float* out = (float*)d_out;

    char* ws = (char*)d_ws;
    u16* qkv_wt = (u16*)ws;  ws += (size_t)3072 * 1024 * 2;   // 6 MB
    u16* out_wt = (u16*)ws;  ws += (size_t)1024 * 1024 * 2;   // 2 MB
    u16* xb     = (u16*)ws;  ws += (size_t)4096 * 1024 * 2;   // 8 MB (also attn out)
    u16* qb     = (u16*)ws;  ws += (size_t)4096 * 1024 * 2;   // 8 MB
    u16* kb     = (u16*)ws;  ws += (size_t)4096 * 1024 * 2;   // 8 MB
    u16* vb     = (u16*)ws;                                    // 8 MB  (total 40 MB)

    cast_f32_bf16<<<4096, 256, 0, stream>>>(x, xb, 4096 * 1024 / 4);
    transpose_cast<<<dim3(96, 32), 256, 0, stream>>>(qkv_w, qkv_wt, 1024, 3072);
    transpose_cast<<<dim3(32, 32), 256, 0, stream>>>(out_w, out_wt, 1024, 1024);

    gemm_bt<1><<<dim3(24, 32), 256, 0, stream>>>(xb, qkv_wt, qkv_b, nullptr,
                                                 qb, kb, vb, 4096, 3072, 1024);
    flash_attn<<<dim3(32, 32), 256, 0, stream>>>(qb, kb, vb, xb);
    gemm_bt<0><<<dim3(8, 32), 256, 0, stream>>>(xb, out_wt, out_b, out,
                                                nullptr, nullptr, nullptr, 4096, 1024, 1024);
}